// Round 1
// 1028.773 us; speedup vs baseline: 1.0006x; 1.0006x over previous
//
#include <hip/hip_runtime.h>

#define Hh 480
#define Ww 480
#define Cc 32
#define Bb 32
#define Ll 120
#define CHUNKS 15   // 480*480/15 = 15360 elems = 3840 float4 per chunk; /256 thr = 15 iters
#define PITCH 121   // odd pitch: phase-C row pairs rotate LDS banks

// Kernel 1: per-(batch,chunk) partial sums of the channel-1 agent mask.
// part layout: int[32][CHUNKS][3] = {cnt, sum_y, sum_x}
__global__ __launch_bounds__(256) void agent_pos_partial(const float* __restrict__ in,
                                                         int* __restrict__ part) {
    const int b     = blockIdx.x / CHUNKS;
    const int chunk = blockIdx.x % CHUNKS;
    const float4* ch = (const float4*)(in + ((size_t)b * Cc + 1) * (size_t)(Hh * Ww));
    const int base = chunk * (Hh * Ww / CHUNKS / 4);  // float4 index base

    int cnt = 0, sy = 0, sx = 0;
#pragma unroll
    for (int it = 0; it < 15; ++it) {
        const int fidx = base + it * 256 + threadIdx.x;
        const float4 v = ch[fidx];
        const int lin = fidx * 4;
        if (v.x == 1.0f) { cnt++; sy += (lin    ) / Ww; sx += (lin    ) % Ww; }
        if (v.y == 1.0f) { cnt++; sy += (lin + 1) / Ww; sx += (lin + 1) % Ww; }
        if (v.z == 1.0f) { cnt++; sy += (lin + 2) / Ww; sx += (lin + 2) % Ww; }
        if (v.w == 1.0f) { cnt++; sy += (lin + 3) / Ww; sx += (lin + 3) % Ww; }
    }
    // wave64 shuffle reduction
#pragma unroll
    for (int off = 32; off > 0; off >>= 1) {
        cnt += __shfl_down(cnt, off);
        sy  += __shfl_down(sy,  off);
        sx  += __shfl_down(sx,  off);
    }
    __shared__ int lds[4][3];
    const int wave = threadIdx.x >> 6;
    const int lane = threadIdx.x & 63;
    if (lane == 0) { lds[wave][0] = cnt; lds[wave][1] = sy; lds[wave][2] = sx; }
    __syncthreads();
    if (threadIdx.x == 0) {
        int c = 0, y = 0, x = 0;
#pragma unroll
        for (int w = 0; w < 4; ++w) { c += lds[w][0]; y += lds[w][1]; x += lds[w][2]; }
        int* o = part + ((size_t)b * CHUNKS + chunk) * 3;
        o[0] = c; o[1] = y; o[2] = x;
    }
}

// Kernel 2: one block per (b, c). Phase B stages the <=120x120 crop region into
// LDS with coalesced row copies (each HBM byte fetched exactly once). Phase C:
// 480 lanes each own (tyo, xo); x-interp params computed once; 30-row loop of
// 4 stride-1 LDS reads + bilinear + coalesced store.
__global__ __launch_bounds__(512) void crop_resize_lds(const float* __restrict__ in,
                                                       const int* __restrict__ part,
                                                       float* __restrict__ out) {
    const int bc = blockIdx.x;      // b*32 + c; input offset = bc * H * W
    const int b  = bc >> 5;

    // reduce the 15 per-chunk partials (uniform addresses -> scalar loads)
    int cnt = 0, sy = 0, sx = 0;
    const int* p = part + (size_t)b * CHUNKS * 3;
#pragma unroll
    for (int i = 0; i < CHUNKS; ++i) { cnt += p[i*3]; sy += p[i*3+1]; sx += p[i*3+2]; }

    const float denom = fmaxf((float)cnt, 1.0f);
    const int py = (cnt > 0) ? (int)rintf((float)sy / denom) : (Hh / 2);  // rintf = round-half-even, matches jnp.round
    const int px = (cnt > 0) ? (int)rintf((float)sx / denom) : (Ww / 2);

    const int y_start = max(py - Ll / 2, 0);
    const int y_end   = min(py + Ll / 2, Hh);
    const int x_start = max(px - Ll / 2, 0);
    const int x_end   = min(px + Ll / 2, Ww);
    const int ry = y_end - y_start;   // <= 120
    const int rx = x_end - x_start;   // <= 120

    __shared__ float tile[Ll * PITCH];   // 120*121*4 = 58,080 B -> 2 blocks/CU

    const int t = threadIdx.x;
    const float* src = in + (size_t)bc * (Hh * Ww) + (size_t)y_start * Ww + x_start;

    // Phase B: coalesced copy, 4 rows in flight (one per 128-thread group)
    {
        const int r0   = t >> 7;     // 0..3
        const int xcol = t & 127;    // 0..127, guard against rx
        if (xcol < rx) {
            for (int r = r0; r < ry; r += 4) {
                tile[r * PITCH + xcol] = src[(size_t)r * Ww + xcol];
            }
        }
    }
    __syncthreads();

    // Phase C: bilinear resample from LDS
    if (t < 4 * Ll) {
        const int tyo = t / Ll;          // 0..3
        const int xo  = t - tyo * Ll;    // 0..119

        const float ix  = (float)xo + 0.5f;
        const float sxf = fmaxf(ix * ((float)rx / (float)Ll) - 0.5f, 0.0f);
        const int   x0  = (int)floorf(sxf);
        const int   x1  = min(x0 + 1, rx - 1);
        const float wx  = sxf - (float)x0;

        const float ry_scale = (float)ry / (float)Ll;
        float* ob = out + (size_t)bc * (Ll * Ll) + xo;

        for (int yo = tyo; yo < Ll; yo += 4) {
            const float iy  = (float)yo + 0.5f;
            const float syf = fmaxf(iy * ry_scale - 0.5f, 0.0f);
            const int   y0  = (int)floorf(syf);
            const int   y1  = min(y0 + 1, ry - 1);
            const float wy  = syf - (float)y0;

            const float* row0 = tile + y0 * PITCH;
            const float* row1 = tile + y1 * PITCH;
            const float v00 = row0[x0];
            const float v01 = row0[x1];
            const float v10 = row1[x0];
            const float v11 = row1[x1];
            const float top = v00 * (1.0f - wx) + v01 * wx;
            const float bot = v10 * (1.0f - wx) + v11 * wx;
            ob[(size_t)yo * Ll] = top * (1.0f - wy) + bot * wy;
        }
    }
}

extern "C" void kernel_launch(void* const* d_in, const int* in_sizes, int n_in,
                              void* d_out, int out_size, void* d_ws, size_t ws_size,
                              hipStream_t stream) {
    const float* in  = (const float*)d_in[0];
    float*       out = (float*)d_out;
    int*         part = (int*)d_ws;   // 32*15*3 ints = 5760 B

    agent_pos_partial<<<Bb * CHUNKS, 256, 0, stream>>>(in, part);
    crop_resize_lds<<<Bb * Cc, 512, 0, stream>>>(in, part, out);
}